// Round 5
// baseline (657.472 us; speedup 1.0000x reference)
//
#include <hip/hip_runtime.h>
#include <hip/hip_bf16.h>

// LFA_self — 3-kernel pipeline for MI355X.
// scores = Xq (Wq Wk^T) Xk^T + g(t2); out = attn . (Xv (Wv Wo)) + (bv Wo + bo).
// Round-5 fixes: (a) NO local arrays in staging (explicit float4/uint4 regs;
// round<=4 spilled x[16]/wpk[8] to scratch: +300MB phantom HBM writes),
// (b) dense lane mapping: phase A = 1 float4/lane lane-consecutive (global
// inst covers contiguous 512B), projection reads LDS instead of strided HBM.

#define NT 49
#define TOKS 16384
#define HSL 1024
#define SLOT 3200            // floats per partial slot: 49x64 scores + 64 g-tail

typedef __attribute__((ext_vector_type(8))) short bf16x8;
typedef __attribute__((ext_vector_type(4))) float f32x4;

__device__ __forceinline__ ushort f2bf(float f) {
    union { float f; unsigned u; } v; v.f = f;
    return (ushort)((v.u + 0x7fffu + ((v.u >> 16) & 1u)) >> 16);   // RNE
}
__device__ __forceinline__ unsigned pk2(float f0, float f1) {
    return (unsigned)f2bf(f0) | ((unsigned)f2bf(f1) << 16);
}
// y[c2] = sum_c x[c] * W[c*16+c2], x given as 4 float4s (all static indexing)
__device__ __forceinline__ float dot16(const float* __restrict__ W, int c2,
    float4 a0, float4 a1, float4 a2, float4 a3) {
    return a0.x*W[c2]     + a0.y*W[16+c2]  + a0.z*W[32+c2]  + a0.w*W[48+c2]
         + a1.x*W[64+c2]  + a1.y*W[80+c2]  + a1.z*W[96+c2]  + a1.w*W[112+c2]
         + a2.x*W[128+c2] + a2.y*W[144+c2] + a2.z*W[160+c2] + a2.w*W[176+c2]
         + a3.x*W[192+c2] + a3.y*W[208+c2] + a3.z*W[224+c2] + a3.w*W[240+c2];
}
__device__ __forceinline__ void proj16(const float* __restrict__ W,
    float4 x0, float4 x1, float4 x2, float4 x3, uint4& lo, uint4& hi) {
    lo.x = pk2(dot16(W, 0,x0,x1,x2,x3), dot16(W, 1,x0,x1,x2,x3));
    lo.y = pk2(dot16(W, 2,x0,x1,x2,x3), dot16(W, 3,x0,x1,x2,x3));
    lo.z = pk2(dot16(W, 4,x0,x1,x2,x3), dot16(W, 5,x0,x1,x2,x3));
    lo.w = pk2(dot16(W, 6,x0,x1,x2,x3), dot16(W, 7,x0,x1,x2,x3));
    hi.x = pk2(dot16(W, 8,x0,x1,x2,x3), dot16(W, 9,x0,x1,x2,x3));
    hi.y = pk2(dot16(W,10,x0,x1,x2,x3), dot16(W,11,x0,x1,x2,x3));
    hi.z = pk2(dot16(W,12,x0,x1,x2,x3), dot16(W,13,x0,x1,x2,x3));
    hi.w = pk2(dot16(W,14,x0,x1,x2,x3), dot16(W,15,x0,x1,x2,x3));
}

// ================= K1: partial scores, grid (b,h,s)=1024, 256 thr ==========
__global__ __launch_bounds__(256, 2) void k_scores(
    const float* __restrict__ qin, const float* __restrict__ kin,
    const float* __restrict__ Wq, const float* __restrict__ bq,
    const float* __restrict__ Wk, float* __restrict__ ws1)
{
    __shared__ ushort bufA[64*128];   // Yq bf16, 256B rows, XOR-swizzled
    __shared__ ushort bufB[64*128];   // Xk bf16, swizzled
    __shared__ float  rawQ[NT*128];   // raw fp32 q chunk (dense-staged)
    __shared__ float  Msh[256];       // Wq Wk^T
    __shared__ float  wkbqSh[16];     // Wk bq
    __shared__ float  gSh[64];

    const int tid  = threadIdx.x;
    const int lane = tid & 63;
    const int wv   = tid >> 6;        // 0..3
    const int s    = blockIdx.x & 1;
    const int h    = (blockIdx.x >> 1) & 15;
    const int b    = blockIdx.x >> 5;

    const float* qbase = qin + (size_t)b*NT*TOKS + h*HSL + s*512;
    const float* kbase = kin + (size_t)b*NT*TOKS + h*HSL + s*512;

    {   // init: zero pad rows (49..63 must be 0 for MFMA), weight products
        unsigned* z0 = (unsigned*)bufA; unsigned* z1 = (unsigned*)bufB;
        for (int i = tid; i < 4096; i += 256) { z0[i] = 0u; z1[i] = 0u; }
        const int c1 = tid >> 4, c2 = tid & 15;
        float m = 0.f;
        #pragma unroll
        for (int f = 0; f < 16; ++f) m += Wq[c1*16+f] * Wk[c2*16+f];
        Msh[tid] = m;
        if (tid < 16) {
            float wb = 0.f;
            #pragma unroll
            for (int g = 0; g < 16; ++g) wb += Wk[tid*16+g] * bq[g];
            wkbqSh[tid] = wb;
        }
        if (tid < 64) gSh[tid] = 0.f;
    }
    __syncthreads();

    f32x4 accS[4];
    #pragma unroll
    for (int nt = 0; nt < 4; ++nt) accS[nt] = (f32x4){0.f,0.f,0.f,0.f};

    for (int kc = 0; kc < 4; ++kc) {
        // ---- phase A (dense): q raw -> rawQ; k cvt -> bufB; 1 float4/lane
        for (int p = tid; p < 3136; p += 256) {
            const int isK = p >= 1568;
            const int pp  = isK ? p - 1568 : p;
            const int t   = pp >> 5, f4 = pp & 31;
            const float4 a = *(const float4*)((isK ? kbase : qbase)
                                + (size_t)t*TOKS + kc*128 + f4*4);
            if (!isK) {
                *(float4*)&rawQ[t*128 + f4*4] = a;
            } else {
                uint2 w; w.x = pk2(a.x, a.y); w.y = pk2(a.z, a.w);
                const int addr = (t*256 + f4*8) ^ ((t & 7) << 4);
                *(uint2*)((char*)bufB + addr) = w;
                const float* wb = wkbqSh + (f4 & 3)*4;   // channel base (f4*4)%16
                const float pg = a.x*wb[0] + a.y*wb[1] + a.z*wb[2] + a.w*wb[3];
                if (pg != 0.f) atomicAdd(&gSh[t], pg);   // bq==0 -> pg==0 exactly
            }
        }
        __syncthreads();
        // ---- phase B: Yq = rawQ * M (LDS reads), write bufA swizzled
        for (int p = tid; p < 392; p += 256) {
            const int t = p >> 3, si = p & 7;
            const float* rq = rawQ + t*128 + si*16;
            const float4 x0 = *(const float4*)(rq);
            const float4 x1 = *(const float4*)(rq + 4);
            const float4 x2 = *(const float4*)(rq + 8);
            const float4 x3 = *(const float4*)(rq + 12);
            uint4 lo, hi;
            proj16(Msh, x0, x1, x2, x3, lo, hi);
            const int bo_ = t*256 + si*32, sw = (t & 7) << 4;
            *(uint4*)((char*)bufA + ((bo_     ) ^ sw)) = lo;
            *(uint4*)((char*)bufA + ((bo_ + 16) ^ sw)) = hi;
        }
        __syncthreads();
        // ---- MFMA: K-chunk 128 = 4 ksteps
        #pragma unroll
        for (int ks = 0; ks < 4; ++ks) {
            const int ra  = wv*16 + (lane & 15);
            const int abo = (ra*256 + (ks*32 + (lane >> 4)*8)*2) ^ ((ra & 7) << 4);
            const bf16x8 af = *(const bf16x8*)((const char*)bufA + abo);
            #pragma unroll
            for (int nt = 0; nt < 4; ++nt) {
                const int rb  = nt*16 + (lane & 15);
                const int bbo = (rb*256 + (ks*32 + (lane >> 4)*8)*2) ^ ((rb & 7) << 4);
                const bf16x8 bf = *(const bf16x8*)((const char*)bufB + bbo);
                accS[nt] = __builtin_amdgcn_mfma_f32_16x16x32_bf16(af, bf, accS[nt], 0, 0, 0);
            }
        }
        __syncthreads();
    }

    float* slot = ws1 + (size_t)blockIdx.x * SLOT;
    #pragma unroll
    for (int nt = 0; nt < 4; ++nt) {
        const int col = nt*16 + (lane & 15);
        #pragma unroll
        for (int r = 0; r < 4; ++r) {
            const int row = wv*16 + (lane >> 4)*4 + r;
            if (row < NT) slot[row*64 + col] = accS[nt][r];
        }
    }
    if (tid < 64) slot[3136 + tid] = gSh[tid];
}

// ================= K2: reduce + softmax, grid (b,h)=512, 256 thr ===========
__global__ __launch_bounds__(256, 2) void k_softmax(
    const float* __restrict__ ws1, float* __restrict__ attnp,
    ushort* __restrict__ ws2)
{
    __shared__ float sS[NT*69];
    __shared__ float sG[64];
    const int tid = threadIdx.x;
    const float* slotA = ws1 + (size_t)blockIdx.x * 2 * SLOT;
    const float* slotB = slotA + SLOT;

    for (int p = tid; p < 784; p += 256) {
        const int row = p >> 4, c4 = (p & 15) * 4;
        const float4 a  = *(const float4*)(slotA + row*64 + c4);
        const float4 bb = *(const float4*)(slotB + row*64 + c4);
        sS[row*69 + c4 + 0] = a.x + bb.x;
        sS[row*69 + c4 + 1] = a.y + bb.y;
        sS[row*69 + c4 + 2] = a.z + bb.z;
        sS[row*69 + c4 + 3] = a.w + bb.w;
    }
    if (tid < 64) sG[tid] = slotA[3136 + tid] + slotB[3136 + tid];
    __syncthreads();

    if (tid < NT) {
        float mx = -1e30f;
        for (int j = 0; j < NT; ++j) {
            const float v = (sS[tid*69 + j] + sG[j]) * 0.03125f;
            sS[tid*69 + j] = v;
            mx = fmaxf(mx, v);
        }
        float ssum = 0.f;
        for (int j = 0; j < NT; ++j) {
            const float e = __expf(sS[tid*69 + j] - mx);
            sS[tid*69 + j] = e; ssum += e;
        }
        const float inv = 1.0f / ssum;
        for (int j = 0; j < NT; ++j) sS[tid*69 + j] *= inv;
    }
    __syncthreads();

    float* ab = attnp + (size_t)blockIdx.x * (NT*NT);
    for (int p = tid; p < NT*NT; p += 256) {
        const int t = p / NT, j = p - t*NT;
        ab[p] = sS[t*69 + j];
    }
    ushort* w2 = ws2 + (size_t)blockIdx.x * 4096;   // 64x64 bf16, zero-padded
    for (int p = tid; p < 4096; p += 256) {
        const int t = p >> 6, j = p & 63;
        const float v = (t < NT && j < NT) ? sS[t*69 + j] : 0.f;
        w2[p] = f2bf(v);
    }
}

// ================= K3: out = attn.Z + bvo, grid (b,h,kc)=4096, 256 thr =====
__global__ __launch_bounds__(256, 3) void k_out(
    const float* __restrict__ vin,
    const float* __restrict__ Wv, const float* __restrict__ bv,
    const float* __restrict__ Wo, const float* __restrict__ bo,
    const ushort* __restrict__ ws2, float* __restrict__ out)
{
    __shared__ float  blob[NT*132];   // 25.9 KB; rawV (25.1 KB) aliases it
    __shared__ ushort Z[64*128];      // Xv*Wvo bf16, 256B rows, swizzled
    __shared__ float  WvoSh[256];
    __shared__ float  bvoSh[16];
    float* rawV = blob;

    const int tid  = threadIdx.x;
    const int lane = tid & 63;
    const int wv   = tid >> 6;        // 0..3 -> M-tile
    const int kc   = blockIdx.x & 7;
    const int h    = (blockIdx.x >> 3) & 15;
    const int b    = blockIdx.x >> 7;
    const float* vbase = vin + (size_t)b*NT*TOKS + h*HSL;

    {
        unsigned* z = (unsigned*)Z;
        for (int i = tid; i < 4096; i += 256) z[i] = 0u;   // pad rows 49..63
        const int c1 = tid >> 4, c2 = tid & 15;
        float wvo = 0.f;
        #pragma unroll
        for (int f = 0; f < 16; ++f) wvo += Wv[c1*16+f] * Wo[f*16+c2];
        WvoSh[tid] = wvo;
        if (tid < 16) {
            float s2 = 0.f;
            #pragma unroll
            for (int g = 0; g < 16; ++g) s2 += bv[g]*Wo[g*16+tid];
            bvoSh[tid] = s2 + bo[tid];
        }
    }
    __syncthreads();

    // ---- phase A (dense): raw v chunk -> rawV
    for (int p = tid; p < 1568; p += 256) {
        const int t = p >> 5, f4 = p & 31;
        const float4 a = *(const float4*)(vbase + (size_t)t*TOKS + kc*128 + f4*4);
        *(float4*)&rawV[t*128 + f4*4] = a;
    }
    __syncthreads();

    // ---- phase B: Z = rawV * Wvo, swizzled bf16
    for (int p = tid; p < 392; p += 256) {
        const int t = p >> 3, si = p & 7;
        const float* rv = rawV + t*128 + si*16;
        const float4 x0 = *(const float4*)(rv);
        const float4 x1 = *(const float4*)(rv + 4);
        const float4 x2 = *(const float4*)(rv + 8);
        const float4 x3 = *(const float4*)(rv + 12);
        uint4 lo, hi;
        proj16(WvoSh, x0, x1, x2, x3, lo, hi);
        const int bo_ = t*256 + si*32, sw = (t & 7) << 4;
        *(uint4*)((char*)Z + ((bo_     ) ^ sw)) = lo;
        *(uint4*)((char*)Z + ((bo_ + 16) ^ sw)) = hi;
    }

    // A-fragments straight from ws2 (L2-hot 8 KB tile, plain [64][64] layout)
    const ushort* w2 = ws2 + ((size_t)(b*16 + h)) * 4096;
    const int ra = wv*16 + (lane & 15);
    const bf16x8 af0 = *(const bf16x8*)(w2 + ra*64 +      (lane >> 4)*8);
    const bf16x8 af1 = *(const bf16x8*)(w2 + ra*64 + 32 + (lane >> 4)*8);
    __syncthreads();   // Z staged

    f32x4 accV[8];
    #pragma unroll
    for (int nt = 0; nt < 8; ++nt) accV[nt] = (f32x4){0.f,0.f,0.f,0.f};
    #pragma unroll
    for (int ks = 0; ks < 2; ++ks) {
        const bf16x8 af = ks ? af1 : af0;
        #pragma unroll
        for (int nt = 0; nt < 8; ++nt) {
            const int n = nt*16 + (lane & 15);
            bf16x8 bf;
            #pragma unroll
            for (int j = 0; j < 8; ++j) {       // u16 gather: B[k=t2][n=d]
                const int r2  = ks*32 + (lane >> 4)*8 + j;
                const int bo_ = (r2*256 + n*2) ^ ((r2 & 7) << 4);
                bf[j] = *(const short*)((const char*)Z + bo_);
            }
            accV[nt] = __builtin_amdgcn_mfma_f32_16x16x32_bf16(af, bf, accV[nt], 0, 0, 0);
        }
    }
    __syncthreads();   // all Z + rawV reads done; blob reusable as fp32 V~

    #pragma unroll
    for (int nt = 0; nt < 8; ++nt) {
        const int n = nt*16 + (lane & 15);
        const float bias = bvoSh[n & 15];
        #pragma unroll
        for (int r = 0; r < 4; ++r) {
            const int row = wv*16 + (lane >> 4)*4 + r;
            if (row < NT) blob[row*132 + n] = accV[nt][r] + bias;
        }
    }
    __syncthreads();

    // dense stores: float4 per lane, lane-contiguous (512B segments per token)
    for (int p = tid; p < 1568; p += 256) {
        const int t = p >> 5, q = p & 31;
        const float4 vv = *(const float4*)&blob[t*132 + q*4];
        float* dst = out + (size_t)(b*NT + t)*TOKS + h*HSL + kc*128 + q*4;
        *(float4*)dst = vv;
    }
}

extern "C" void kernel_launch(void* const* d_in, const int* in_sizes, int n_in,
                              void* d_out, int out_size, void* d_ws, size_t ws_size,
                              hipStream_t stream) {
    const float* v  = (const float*)d_in[0];
    const float* k  = (const float*)d_in[1];
    const float* q  = (const float*)d_in[2];
    const float* Wq = (const float*)d_in[3];
    const float* bq = (const float*)d_in[4];
    const float* Wk = (const float*)d_in[5];
    const float* bk = (const float*)d_in[6];   // softmax-row-invariant; unused
    const float* Wv = (const float*)d_in[7];
    const float* bv = (const float*)d_in[8];
    const float* Wo = (const float*)d_in[9];
    const float* bo = (const float*)d_in[10];
    (void)bk; (void)in_sizes; (void)n_in; (void)ws_size; (void)out_size;

    float*  outp  = (float*)d_out;
    float*  attnp = outp + (size_t)32 * 49 * 16384;     // out | attn concat
    float*  ws1   = (float*)d_ws;                       // 1024*3200 fp32 = 13.1 MB
    ushort* ws2   = (ushort*)(ws1 + (size_t)1024*SLOT); // 512*4096 bf16 = 4 MB

    k_scores <<<dim3(1024), dim3(256), 0, stream>>>(q, k, Wq, bq, Wk, ws1);
    k_softmax<<<dim3(512),  dim3(256), 0, stream>>>(ws1, attnp, ws2);
    k_out    <<<dim3(4096), dim3(256), 0, stream>>>(v, Wv, bv, Wo, bo, ws2, outp);
}

// Round 6
// 186.350 us; speedup vs baseline: 3.5281x; 3.5281x over previous
//
#include <hip/hip_runtime.h>
#include <hip/hip_bf16.h>

// LFA_self — 3-kernel pipeline for MI355X (round 6).
// scores = Xq (Wq Wk^T) Xk^T + g(t2); out = attn . (Xv (Wv Wo)) + (bv Wo + bo).
// Round-6: staging does projection with per-thread REGISTER W (preloaded once)
// + 4-lane shfl butterfly; V is stored transposed pair-packed (Zt) so MFMA
// B-fragments are single ds_read_b128 (no u16 gathers -> no spill pressure).

#define NT 49
#define TOKS 16384
#define HSL 1024
#define SLOT 3200            // floats per partial slot: 49x64 scores + 64 g-tail
#define ZSWZ(n) (((((n) & 7) ^ (((n) >> 3) & 7))) << 4)

typedef __attribute__((ext_vector_type(8))) short bf16x8;
typedef __attribute__((ext_vector_type(4))) float f32x4;

__device__ __forceinline__ ushort f2bf(float f) {
    union { float f; unsigned u; } v; v.f = f;
    return (ushort)((v.u + 0x7fffu + ((v.u >> 16) & 1u)) >> 16);   // RNE
}
__device__ __forceinline__ unsigned pk2(float f0, float f1) {
    return (unsigned)f2bf(f0) | ((unsigned)f2bf(f1) << 16);
}
__device__ __forceinline__ float4 f4mul(float s, float4 w) {
    return make_float4(s*w.x, s*w.y, s*w.z, s*w.w);
}
__device__ __forceinline__ float4 f4fma(float s, float4 w, float4 a) {
    a.x = fmaf(s, w.x, a.x); a.y = fmaf(s, w.y, a.y);
    a.z = fmaf(s, w.z, a.z); a.w = fmaf(s, w.w, a.w);
    return a;
}
__device__ __forceinline__ float red4s(float v) {
    v += __shfl_xor(v, 1); v += __shfl_xor(v, 2); return v;
}
__device__ __forceinline__ float4 red4v(float4 v) {
    return make_float4(red4s(v.x), red4s(v.y), red4s(v.z), red4s(v.w));
}

// W preload: 16 named float4 = rows (lane&3)*4..+3 of a 16x16 row-major matrix
#define W_DECL(mb) \
    const float4 W00 = *(const float4*)((mb)+ 0), W01 = *(const float4*)((mb)+ 4), \
                 W02 = *(const float4*)((mb)+ 8), W03 = *(const float4*)((mb)+12), \
                 W10 = *(const float4*)((mb)+16), W11 = *(const float4*)((mb)+20), \
                 W12 = *(const float4*)((mb)+24), W13 = *(const float4*)((mb)+28), \
                 W20 = *(const float4*)((mb)+32), W21 = *(const float4*)((mb)+36), \
                 W22 = *(const float4*)((mb)+40), W23 = *(const float4*)((mb)+44), \
                 W30 = *(const float4*)((mb)+48), W31 = *(const float4*)((mb)+52), \
                 W32 = *(const float4*)((mb)+56), W33 = *(const float4*)((mb)+60)

#define PROJ_BFLY(a, y0, y1, y2, y3) \
    float4 y0 = f4mul((a).x, W00); y0 = f4fma((a).y, W10, y0); \
    y0 = f4fma((a).z, W20, y0);    y0 = f4fma((a).w, W30, y0); \
    float4 y1 = f4mul((a).x, W01); y1 = f4fma((a).y, W11, y1); \
    y1 = f4fma((a).z, W21, y1);    y1 = f4fma((a).w, W31, y1); \
    float4 y2 = f4mul((a).x, W02); y2 = f4fma((a).y, W12, y2); \
    y2 = f4fma((a).z, W22, y2);    y2 = f4fma((a).w, W32, y2); \
    float4 y3 = f4mul((a).x, W03); y3 = f4fma((a).y, W13, y3); \
    y3 = f4fma((a).z, W23, y3);    y3 = f4fma((a).w, W33, y3); \
    y0 = red4v(y0); y1 = red4v(y1); y2 = red4v(y2); y3 = red4v(y3)

// ================= K1: partial scores, grid (b,h,s)=1024, 256 thr ==========
__global__ __launch_bounds__(256, 2) void k_scores(
    const float* __restrict__ qin, const float* __restrict__ kin,
    const float* __restrict__ Wq, const float* __restrict__ bq,
    const float* __restrict__ Wk, float* __restrict__ ws1)
{
    __shared__ ushort bufA[64*128];   // Yq bf16, 256B rows, XOR-swizzled
    __shared__ ushort bufB[64*128];   // Xk bf16, swizzled
    __shared__ float  Msh[256];       // Wq Wk^T
    __shared__ float  wkbqSh[16];     // Wk bq
    __shared__ float  gSh[64];

    const int tid  = threadIdx.x;
    const int lane = tid & 63;
    const int wv   = tid >> 6;        // 0..3
    const int s    = blockIdx.x & 1;
    const int h    = (blockIdx.x >> 1) & 15;
    const int b    = blockIdx.x >> 5;

    const float* qbase = qin + (size_t)b*NT*TOKS + h*HSL + s*512;
    const float* kbase = kin + (size_t)b*NT*TOKS + h*HSL + s*512;

    {   // init: zero pad rows (49..63 must be 0 for MFMA), weight products
        unsigned* z0 = (unsigned*)bufA; unsigned* z1 = (unsigned*)bufB;
        for (int i = tid; i < 4096; i += 256) { z0[i] = 0u; z1[i] = 0u; }
        const int c1 = tid >> 4, c2 = tid & 15;
        float m = 0.f;
        #pragma unroll
        for (int f = 0; f < 16; ++f) m += Wq[c1*16+f] * Wk[c2*16+f];
        Msh[tid] = m;
        if (tid < 16) {
            float wb = 0.f;
            #pragma unroll
            for (int g = 0; g < 16; ++g) wb += Wk[tid*16+g] * bq[g];
            wkbqSh[tid] = wb;
        }
        if (tid < 64) gSh[tid] = 0.f;
    }
    __syncthreads();

    const float* mb = Msh + (lane & 3)*64;     // this lane's 4 rows of M
    W_DECL(mb);

    f32x4 accS[4];
    #pragma unroll
    for (int nt = 0; nt < 4; ++nt) accS[nt] = (f32x4){0.f,0.f,0.f,0.f};

    for (int kc = 0; kc < 4; ++kc) {
        // ---- q: dense float4 load -> register proj (butterfly) -> bufA
        for (int p = tid; p < 1600; p += 256) {
            const int t = p >> 5, f4 = p & 31;
            float4 a = make_float4(0.f, 0.f, 0.f, 0.f);
            if (t < NT) a = *(const float4*)(qbase + (size_t)t*TOKS + kc*128 + f4*4);
            PROJ_BFLY(a, y0, y1, y2, y3);
            const int r = f4 & 3;
            uint2 w;
            if      (r == 0) { w.x = pk2(y0.x, y0.y); w.y = pk2(y0.z, y0.w); }
            else if (r == 1) { w.x = pk2(y1.x, y1.y); w.y = pk2(y1.z, y1.w); }
            else if (r == 2) { w.x = pk2(y2.x, y2.y); w.y = pk2(y2.z, y2.w); }
            else             { w.x = pk2(y3.x, y3.y); w.y = pk2(y3.z, y3.w); }
            const int addr = (t*256 + (f4 >> 2)*32 + r*8) ^ ((t & 7) << 4);
            *(uint2*)((char*)bufA + addr) = w;
        }
        // ---- k: dense float4 load -> bf16 convert -> bufB
        for (int p = tid; p < 1568; p += 256) {
            const int t = p >> 5, f4 = p & 31;
            const float4 a = *(const float4*)(kbase + (size_t)t*TOKS + kc*128 + f4*4);
            uint2 w; w.x = pk2(a.x, a.y); w.y = pk2(a.z, a.w);
            const int addr = (t*256 + f4*8) ^ ((t & 7) << 4);
            *(uint2*)((char*)bufB + addr) = w;
            const float* wb = wkbqSh + (f4 & 3)*4;
            const float pg = a.x*wb[0] + a.y*wb[1] + a.z*wb[2] + a.w*wb[3];
            if (pg != 0.f) atomicAdd(&gSh[t], pg);   // bq==0 -> never fires
        }
        __syncthreads();
        #pragma unroll
        for (int ks = 0; ks < 4; ++ks) {
            const int ra  = wv*16 + (lane & 15);
            const int abo = (ra*256 + (ks*32 + (lane >> 4)*8)*2) ^ ((ra & 7) << 4);
            const bf16x8 af = *(const bf16x8*)((const char*)bufA + abo);
            #pragma unroll
            for (int nt = 0; nt < 4; ++nt) {
                const int rb  = nt*16 + (lane & 15);
                const int bbo = (rb*256 + (ks*32 + (lane >> 4)*8)*2) ^ ((rb & 7) << 4);
                const bf16x8 bf = *(const bf16x8*)((const char*)bufB + bbo);
                accS[nt] = __builtin_amdgcn_mfma_f32_16x16x32_bf16(af, bf, accS[nt], 0, 0, 0);
            }
        }
        __syncthreads();
    }

    float* slot = ws1 + (size_t)blockIdx.x * SLOT;
    #pragma unroll
    for (int nt = 0; nt < 4; ++nt) {
        const int col = nt*16 + (lane & 15);
        #pragma unroll
        for (int r = 0; r < 4; ++r) {
            const int row = wv*16 + (lane >> 4)*4 + r;
            if (row < NT) slot[row*64 + col] = accS[nt][r];
        }
    }
    if (tid < 64) slot[3136 + tid] = gSh[tid];
}

// ================= K2: reduce + softmax, grid (b,h)=512, 256 thr ===========
__global__ __launch_bounds__(256, 2) void k_softmax(
    const float* __restrict__ ws1, float* __restrict__ attnp,
    ushort* __restrict__ ws2)
{
    __shared__ float sS[NT*69];
    __shared__ float sG[64];
    const int tid = threadIdx.x;
    const float* slotA = ws1 + (size_t)blockIdx.x * 2 * SLOT;
    const float* slotB = slotA + SLOT;

    for (int p = tid; p < 784; p += 256) {
        const int row = p >> 4, c4 = (p & 15) * 4;
        const float4 a  = *(const float4*)(slotA + row*64 + c4);
        const float4 bb = *(const float4*)(slotB + row*64 + c4);
        sS[row*69 + c4 + 0] = a.x + bb.x;
        sS[row*69 + c4 + 1] = a.y + bb.y;
        sS[row*69 + c4 + 2] = a.z + bb.z;
        sS[row*69 + c4 + 3] = a.w + bb.w;
    }
    if (tid < 64) sG[tid] = slotA[3136 + tid] + slotB[3136 + tid];
    __syncthreads();

    if (tid < NT) {
        float mx = -1e30f;
        for (int j = 0; j < NT; ++j) {
            const float v = (sS[tid*69 + j] + sG[j]) * 0.03125f;
            sS[tid*69 + j] = v;
            mx = fmaxf(mx, v);
        }
        float ssum = 0.f;
        for (int j = 0; j < NT; ++j) {
            const float e = __expf(sS[tid*69 + j] - mx);
            sS[tid*69 + j] = e; ssum += e;
        }
        const float inv = 1.0f / ssum;
        for (int j = 0; j < NT; ++j) sS[tid*69 + j] *= inv;
    }
    __syncthreads();

    float* ab = attnp + (size_t)blockIdx.x * (NT*NT);
    for (int p = tid; p < NT*NT; p += 256) {
        const int t = p / NT, j = p - t*NT;
        ab[p] = sS[t*69 + j];
    }
    ushort* w2 = ws2 + (size_t)blockIdx.x * 4096;   // 64x64 bf16, zero-padded
    for (int p = tid; p < 4096; p += 256) {
        const int t = p >> 6, j = p & 63;
        const float v = (t < NT && j < NT) ? sS[t*69 + j] : 0.f;
        w2[p] = f2bf(v);
    }
}

// ================= K3: out = attn.Z + bvo, grid (b,h,kc)=4096, 256 thr =====
__global__ __launch_bounds__(256, 2) void k_out(
    const float* __restrict__ vin,
    const float* __restrict__ Wv, const float* __restrict__ bv,
    const float* __restrict__ Wo, const float* __restrict__ bo,
    const ushort* __restrict__ ws2, float* __restrict__ out)
{
    __shared__ unsigned Zt[4096];     // Z^T pair-packed: [128 n][32 kpair] u32
    __shared__ float WvoSh[256];
    __shared__ float bvoSh[16];

    const int tid  = threadIdx.x;
    const int lane = tid & 63;
    const int wv   = tid >> 6;        // 0..3 -> M-tile (token rows)
    const int kc   = blockIdx.x & 7;
    const int h    = (blockIdx.x >> 3) & 15;
    const int b    = blockIdx.x >> 7;
    const float* vbase = vin + (size_t)b*NT*TOKS + h*HSL;

    {
        const int c1 = tid >> 4, c2 = tid & 15;
        float wvo = 0.f;
        #pragma unroll
        for (int f = 0; f < 16; ++f) wvo += Wv[c1*16+f] * Wo[f*16+c2];
        WvoSh[tid] = wvo;
        if (tid < 16) {
            float s2 = 0.f;
            #pragma unroll
            for (int g = 0; g < 16; ++g) s2 += bv[g]*Wo[g*16+tid];
            bvoSh[tid] = s2 + bo[tid];
        }
        // zero k-pairs 25..31 (k rows 50..63; MFMA pad — avoid NaN*0)
        for (int i = tid; i < 1024; i += 256) {
            const int n = i >> 3, pr = 24 + (i & 7);
            if (pr >= 25)
                *(unsigned*)((char*)Zt + ((n*128 + pr*4) ^ ZSWZ(n))) = 0u;
        }
    }
    __syncthreads();

    // A-fragments from ws2 (global, L2/L3-hot; issue early to overlap staging)
    const ushort* w2 = ws2 + ((size_t)(blockIdx.x >> 3)) * 4096;
    const int ra = wv*16 + (lane & 15);
    const bf16x8 af0 = *(const bf16x8*)(w2 + ra*64 +      (lane >> 4)*8);
    const bf16x8 af1 = *(const bf16x8*)(w2 + ra*64 + 32 + (lane >> 4)*8);

    const float* mb = WvoSh + (lane & 3)*64;   // this lane's 4 rows of WvWo
    W_DECL(mb);

    // stage Zt: dense load -> reg proj (butterfly) -> token-pair pack (xor 32)
    for (int p = tid; p < 1600; p += 256) {
        const int t = p >> 5, f4 = p & 31;   // lanes<32: t even; lanes>=32: t+1
        float4 a = make_float4(0.f, 0.f, 0.f, 0.f);
        if (t < NT) a = *(const float4*)(vbase + (size_t)t*TOKS + kc*128 + f4*4);
        PROJ_BFLY(a, y0, y1, y2, y3);
        const int r = f4 & 3;
        float4 sel;
        if      (r == 0) sel = y0;
        else if (r == 1) sel = y1;
        else if (r == 2) sel = y2;
        else             sel = y3;
        float4 po;
        po.x = __shfl_xor(sel.x, 32); po.y = __shfl_xor(sel.y, 32);
        po.z = __shfl_xor(sel.z, 32); po.w = __shfl_xor(sel.w, 32);
        if (lane < 32) {                      // own=even token, po=odd token
            const int n0 = (f4 >> 2)*16 + r*4;
            const int pair = p >> 6;
            *(unsigned*)((char*)Zt + (((n0+0)*128 + pair*4) ^ ZSWZ(n0+0))) = pk2(sel.x, po.x);
            *(unsigned*)((char*)Zt + (((n0+1)*128 + pair*4) ^ ZSWZ(n0+1))) = pk2(sel.y, po.y);
            *(unsigned*)((char*)Zt + (((n0+2)*128 + pair*4) ^ ZSWZ(n0+2))) = pk2(sel.z, po.z);
            *(unsigned*)((char*)Zt + (((n0+3)*128 + pair*4) ^ ZSWZ(n0+3))) = pk2(sel.w, po.w);
        }
    }
    __syncthreads();

    // MFMA + direct global store (4 rows x 64B full sectors per instruction)
    float* obase = out + (size_t)b*NT*TOKS + h*HSL + kc*128;
    #pragma unroll
    for (int nt2 = 0; nt2 < 8; ++nt2) {
        const int n    = nt2*16 + (lane & 15);
        const int swzn = ZSWZ(n);
        const bf16x8 bf0 = *(const bf16x8*)((const char*)Zt + ((n*128 +      (lane >> 4)*16) ^ swzn));
        const bf16x8 bf1 = *(const bf16x8*)((const char*)Zt + ((n*128 + 64 + (lane >> 4)*16) ^ swzn));
        f32x4 acc = (f32x4){0.f, 0.f, 0.f, 0.f};
        acc = __builtin_amdgcn_mfma_f32_16x16x32_bf16(af0, bf0, acc, 0, 0, 0);
        acc = __builtin_amdgcn_mfma_f32_16x16x32_bf16(af1, bf1, acc, 0, 0, 0);
        const float bias = bvoSh[n & 15];
        #pragma unroll
        for (int r2 = 0; r2 < 4; ++r2) {
            const int row = wv*16 + (lane >> 4)*4 + r2;
            if (row < NT) obase[(size_t)row*TOKS + n] = acc[r2] + bias;
        }
    }
}

extern "C" void kernel_launch(void* const* d_in, const int* in_sizes, int n_in,
                              void* d_out, int out_size, void* d_ws, size_t ws_size,
                              hipStream_t stream) {
    const float* v  = (const float*)d_in[0];
    const float* k  = (const float*)d_in[1];
    const float* q  = (const float*)d_in[2];
    const float* Wq = (const float*)d_in[3];
    const float* bq = (const float*)d_in[4];
    const float* Wk = (const float*)d_in[5];
    const float* bk = (const float*)d_in[6];   // softmax-row-invariant; unused
    const float* Wv = (const float*)d_in[7];
    const float* bv = (const float*)d_in[8];
    const float* Wo = (const float*)d_in[9];
    const float* bo = (const float*)d_in[10];
    (void)bk; (void)in_sizes; (void)n_in; (void)ws_size; (void)out_size;

    float*  outp  = (float*)d_out;
    float*  attnp = outp + (size_t)32 * 49 * 16384;     // out | attn concat
    float*  ws1   = (float*)d_ws;                       // 1024*3200 fp32 = 13.1 MB
    ushort* ws2   = (ushort*)(ws1 + (size_t)1024*SLOT); // 512*4096 bf16 = 4 MB

    k_scores <<<dim3(1024), dim3(256), 0, stream>>>(q, k, Wq, bq, Wk, ws1);
    k_softmax<<<dim3(512),  dim3(256), 0, stream>>>(ws1, attnp, ws2);
    k_out    <<<dim3(4096), dim3(256), 0, stream>>>(v, Wv, bv, Wo, bo, ws2, outp);
}

// Round 7
// 174.373 us; speedup vs baseline: 3.7705x; 1.0687x over previous
//
#include <hip/hip_runtime.h>
#include <hip/hip_bf16.h>

// LFA_self — 3-kernel pipeline for MI355X (round 7).
// scores = Xq (Wq Wk^T) Xk^T + g(t2); out = attn . (Xv (Wv Wo)) + (bv Wo + bo).
// Round-7: k_scores K-split 4-way (2048 blocks, 2 chunks each) to break the
// barrier-serialized latency chain; runtime ws_size guard falls back to the
// proven 2-way split if scratch is too small.

#define NT 49
#define TOKS 16384
#define HSL 1024
#define SLOT 3200            // floats per partial slot: 49x64 scores + 64 g-tail
#define ZSWZ(n) (((((n) & 7) ^ (((n) >> 3) & 7))) << 4)

typedef __attribute__((ext_vector_type(8))) short bf16x8;
typedef __attribute__((ext_vector_type(4))) float f32x4;

__device__ __forceinline__ ushort f2bf(float f) {
    union { float f; unsigned u; } v; v.f = f;
    return (ushort)((v.u + 0x7fffu + ((v.u >> 16) & 1u)) >> 16);   // RNE
}
__device__ __forceinline__ unsigned pk2(float f0, float f1) {
    return (unsigned)f2bf(f0) | ((unsigned)f2bf(f1) << 16);
}
__device__ __forceinline__ float4 f4mul(float s, float4 w) {
    return make_float4(s*w.x, s*w.y, s*w.z, s*w.w);
}
__device__ __forceinline__ float4 f4fma(float s, float4 w, float4 a) {
    a.x = fmaf(s, w.x, a.x); a.y = fmaf(s, w.y, a.y);
    a.z = fmaf(s, w.z, a.z); a.w = fmaf(s, w.w, a.w);
    return a;
}
__device__ __forceinline__ float red4s(float v) {
    v += __shfl_xor(v, 1); v += __shfl_xor(v, 2); return v;
}
__device__ __forceinline__ float4 red4v(float4 v) {
    return make_float4(red4s(v.x), red4s(v.y), red4s(v.z), red4s(v.w));
}

// W preload: 16 named float4 = rows (lane&3)*4..+3 of a 16x16 row-major matrix
#define W_DECL(mb) \
    const float4 W00 = *(const float4*)((mb)+ 0), W01 = *(const float4*)((mb)+ 4), \
                 W02 = *(const float4*)((mb)+ 8), W03 = *(const float4*)((mb)+12), \
                 W10 = *(const float4*)((mb)+16), W11 = *(const float4*)((mb)+20), \
                 W12 = *(const float4*)((mb)+24), W13 = *(const float4*)((mb)+28), \
                 W20 = *(const float4*)((mb)+32), W21 = *(const float4*)((mb)+36), \
                 W22 = *(const float4*)((mb)+40), W23 = *(const float4*)((mb)+44), \
                 W30 = *(const float4*)((mb)+48), W31 = *(const float4*)((mb)+52), \
                 W32 = *(const float4*)((mb)+56), W33 = *(const float4*)((mb)+60)

#define PROJ_BFLY(a, y0, y1, y2, y3) \
    float4 y0 = f4mul((a).x, W00); y0 = f4fma((a).y, W10, y0); \
    y0 = f4fma((a).z, W20, y0);    y0 = f4fma((a).w, W30, y0); \
    float4 y1 = f4mul((a).x, W01); y1 = f4fma((a).y, W11, y1); \
    y1 = f4fma((a).z, W21, y1);    y1 = f4fma((a).w, W31, y1); \
    float4 y2 = f4mul((a).x, W02); y2 = f4fma((a).y, W12, y2); \
    y2 = f4fma((a).z, W22, y2);    y2 = f4fma((a).w, W32, y2); \
    float4 y3 = f4mul((a).x, W03); y3 = f4fma((a).y, W13, y3); \
    y3 = f4fma((a).z, W23, y3);    y3 = f4fma((a).w, W33, y3); \
    y0 = red4v(y0); y1 = red4v(y1); y2 = red4v(y2); y3 = red4v(y3)

// ===== K1: partial scores, grid (b,h,s)=512*SPLIT, 256 thr =================
template<int SPLIT, int LOG2S>
__global__ __launch_bounds__(256, 2) void k_scores(
    const float* __restrict__ qin, const float* __restrict__ kin,
    const float* __restrict__ Wq, const float* __restrict__ bq,
    const float* __restrict__ Wk, float* __restrict__ ws1)
{
    __shared__ ushort bufA[64*128];   // Yq bf16, 256B rows, XOR-swizzled
    __shared__ ushort bufB[64*128];   // Xk bf16, swizzled
    __shared__ float  Msh[256];       // Wq Wk^T
    __shared__ float  wkbqSh[16];     // Wk bq
    __shared__ float  gSh[64];

    const int tid  = threadIdx.x;
    const int lane = tid & 63;
    const int wv   = tid >> 6;        // 0..3
    const int s    = blockIdx.x & (SPLIT - 1);
    const int h    = (blockIdx.x >> LOG2S) & 15;
    const int b    = blockIdx.x >> (LOG2S + 4);

    const float* qbase = qin + (size_t)b*NT*TOKS + h*HSL + s*(1024/SPLIT);
    const float* kbase = kin + (size_t)b*NT*TOKS + h*HSL + s*(1024/SPLIT);

    {   // init: zero pad rows (49..63 must be 0 for MFMA), weight products
        unsigned* z0 = (unsigned*)bufA; unsigned* z1 = (unsigned*)bufB;
        for (int i = tid; i < 4096; i += 256) { z0[i] = 0u; z1[i] = 0u; }
        const int c1 = tid >> 4, c2 = tid & 15;
        float m = 0.f;
        #pragma unroll
        for (int f = 0; f < 16; ++f) m += Wq[c1*16+f] * Wk[c2*16+f];
        Msh[tid] = m;
        if (tid < 16) {
            float wb = 0.f;
            #pragma unroll
            for (int g = 0; g < 16; ++g) wb += Wk[tid*16+g] * bq[g];
            wkbqSh[tid] = wb;
        }
        if (tid < 64) gSh[tid] = 0.f;
    }
    __syncthreads();

    const float* mb = Msh + (lane & 3)*64;     // this lane's 4 rows of M
    W_DECL(mb);

    f32x4 accS[4];
    #pragma unroll
    for (int nt = 0; nt < 4; ++nt) accS[nt] = (f32x4){0.f,0.f,0.f,0.f};

    for (int kc = 0; kc < 8/SPLIT; ++kc) {
        // ---- q: dense float4 load -> register proj (butterfly) -> bufA
        for (int p = tid; p < 1600; p += 256) {
            const int t = p >> 5, f4 = p & 31;
            float4 a = make_float4(0.f, 0.f, 0.f, 0.f);
            if (t < NT) a = *(const float4*)(qbase + (size_t)t*TOKS + kc*128 + f4*4);
            PROJ_BFLY(a, y0, y1, y2, y3);
            const int r = f4 & 3;
            uint2 w;
            if      (r == 0) { w.x = pk2(y0.x, y0.y); w.y = pk2(y0.z, y0.w); }
            else if (r == 1) { w.x = pk2(y1.x, y1.y); w.y = pk2(y1.z, y1.w); }
            else if (r == 2) { w.x = pk2(y2.x, y2.y); w.y = pk2(y2.z, y2.w); }
            else             { w.x = pk2(y3.x, y3.y); w.y = pk2(y3.z, y3.w); }
            const int addr = (t*256 + (f4 >> 2)*32 + r*8) ^ ((t & 7) << 4);
            *(uint2*)((char*)bufA + addr) = w;
        }
        // ---- k: dense float4 load -> bf16 convert -> bufB
        for (int p = tid; p < 1568; p += 256) {
            const int t = p >> 5, f4 = p & 31;
            const float4 a = *(const float4*)(kbase + (size_t)t*TOKS + kc*128 + f4*4);
            uint2 w; w.x = pk2(a.x, a.y); w.y = pk2(a.z, a.w);
            const int addr = (t*256 + f4*8) ^ ((t & 7) << 4);
            *(uint2*)((char*)bufB + addr) = w;
            const float* wb = wkbqSh + (f4 & 3)*4;
            const float pg = a.x*wb[0] + a.y*wb[1] + a.z*wb[2] + a.w*wb[3];
            if (pg != 0.f) atomicAdd(&gSh[t], pg);   // bq==0 -> never fires
        }
        __syncthreads();
        #pragma unroll
        for (int ks = 0; ks < 4; ++ks) {
            const int ra  = wv*16 + (lane & 15);
            const int abo = (ra*256 + (ks*32 + (lane >> 4)*8)*2) ^ ((ra & 7) << 4);
            const bf16x8 af = *(const bf16x8*)((const char*)bufA + abo);
            #pragma unroll
            for (int nt = 0; nt < 4; ++nt) {
                const int rb  = nt*16 + (lane & 15);
                const int bbo = (rb*256 + (ks*32 + (lane >> 4)*8)*2) ^ ((rb & 7) << 4);
                const bf16x8 bf = *(const bf16x8*)((const char*)bufB + bbo);
                accS[nt] = __builtin_amdgcn_mfma_f32_16x16x32_bf16(af, bf, accS[nt], 0, 0, 0);
            }
        }
        __syncthreads();
    }

    float* slot = ws1 + (size_t)blockIdx.x * SLOT;
    #pragma unroll
    for (int nt = 0; nt < 4; ++nt) {
        const int col = nt*16 + (lane & 15);
        #pragma unroll
        for (int r = 0; r < 4; ++r) {
            const int row = wv*16 + (lane >> 4)*4 + r;
            if (row < NT) slot[row*64 + col] = accS[nt][r];
        }
    }
    if (tid < 64) slot[3136 + tid] = gSh[tid];
}

// ===== K2: reduce + softmax, grid (b,h)=512, 256 thr =======================
template<int SPLIT>
__global__ __launch_bounds__(256, 2) void k_softmax(
    const float* __restrict__ ws1, float* __restrict__ attnp,
    ushort* __restrict__ ws2)
{
    __shared__ float sS[NT*69];
    __shared__ float sG[64];
    const int tid = threadIdx.x;
    const float* base = ws1 + (size_t)blockIdx.x * SPLIT * SLOT;

    for (int p = tid; p < 784; p += 256) {
        const int row = p >> 4, c4 = (p & 15) * 4;
        float4 acc = *(const float4*)(base + row*64 + c4);
        #pragma unroll
        for (int s = 1; s < SPLIT; ++s) {
            const float4 a = *(const float4*)(base + s*SLOT + row*64 + c4);
            acc.x += a.x; acc.y += a.y; acc.z += a.z; acc.w += a.w;
        }
        sS[row*69 + c4 + 0] = acc.x;
        sS[row*69 + c4 + 1] = acc.y;
        sS[row*69 + c4 + 2] = acc.z;
        sS[row*69 + c4 + 3] = acc.w;
    }
    if (tid < 64) {
        float g = base[3136 + tid];
        #pragma unroll
        for (int s = 1; s < SPLIT; ++s) g += base[s*SLOT + 3136 + tid];
        sG[tid] = g;
    }
    __syncthreads();

    if (tid < NT) {
        float mx = -1e30f;
        for (int j = 0; j < NT; ++j) {
            const float v = (sS[tid*69 + j] + sG[j]) * 0.03125f;
            sS[tid*69 + j] = v;
            mx = fmaxf(mx, v);
        }
        float ssum = 0.f;
        for (int j = 0; j < NT; ++j) {
            const float e = __expf(sS[tid*69 + j] - mx);
            sS[tid*69 + j] = e; ssum += e;
        }
        const float inv = 1.0f / ssum;
        for (int j = 0; j < NT; ++j) sS[tid*69 + j] *= inv;
    }
    __syncthreads();

    float* ab = attnp + (size_t)blockIdx.x * (NT*NT);
    for (int p = tid; p < NT*NT; p += 256) {
        const int t = p / NT, j = p - t*NT;
        ab[p] = sS[t*69 + j];
    }
    ushort* w2 = ws2 + (size_t)blockIdx.x * 4096;   // 64x64 bf16, zero-padded
    for (int p = tid; p < 4096; p += 256) {
        const int t = p >> 6, j = p & 63;
        const float v = (t < NT && j < NT) ? sS[t*69 + j] : 0.f;
        w2[p] = f2bf(v);
    }
}

// ===== K3: out = attn.Z + bvo, grid (b,h,kc)=4096, 256 thr =================
__global__ __launch_bounds__(256, 2) void k_out(
    const float* __restrict__ vin,
    const float* __restrict__ Wv, const float* __restrict__ bv,
    const float* __restrict__ Wo, const float* __restrict__ bo,
    const ushort* __restrict__ ws2, float* __restrict__ out)
{
    __shared__ unsigned Zt[4096];     // Z^T pair-packed: [128 n][32 kpair] u32
    __shared__ float WvoSh[256];
    __shared__ float bvoSh[16];

    const int tid  = threadIdx.x;
    const int lane = tid & 63;
    const int wv   = tid >> 6;        // 0..3 -> M-tile (token rows)
    const int kc   = blockIdx.x & 7;
    const int h    = (blockIdx.x >> 3) & 15;
    const int b    = blockIdx.x >> 7;
    const float* vbase = vin + (size_t)b*NT*TOKS + h*HSL;

    {
        const int c1 = tid >> 4, c2 = tid & 15;
        float wvo = 0.f;
        #pragma unroll
        for (int f = 0; f < 16; ++f) wvo += Wv[c1*16+f] * Wo[f*16+c2];
        WvoSh[tid] = wvo;
        if (tid < 16) {
            float s2 = 0.f;
            #pragma unroll
            for (int g = 0; g < 16; ++g) s2 += bv[g]*Wo[g*16+tid];
            bvoSh[tid] = s2 + bo[tid];
        }
        // zero k-pairs 25..31 (k rows 50..63; MFMA pad — avoid NaN*0)
        for (int i = tid; i < 1024; i += 256) {
            const int n = i >> 3, pr = 24 + (i & 7);
            if (pr >= 25)
                *(unsigned*)((char*)Zt + ((n*128 + pr*4) ^ ZSWZ(n))) = 0u;
        }
    }
    __syncthreads();

    // A-fragments from ws2 (global, L2/L3-hot; issue early to overlap staging)
    const ushort* w2 = ws2 + ((size_t)(blockIdx.x >> 3)) * 4096;
    const int ra = wv*16 + (lane & 15);
    const bf16x8 af0 = *(const bf16x8*)(w2 + ra*64 +      (lane >> 4)*8);
    const bf16x8 af1 = *(const bf16x8*)(w2 + ra*64 + 32 + (lane >> 4)*8);

    const float* mb = WvoSh + (lane & 3)*64;   // this lane's 4 rows of WvWo
    W_DECL(mb);

    // stage Zt: dense load -> reg proj (butterfly) -> token-pair pack (xor 32)
    for (int p = tid; p < 1600; p += 256) {
        const int t = p >> 5, f4 = p & 31;   // lanes<32: t even; lanes>=32: t+1
        float4 a = make_float4(0.f, 0.f, 0.f, 0.f);
        if (t < NT) a = *(const float4*)(vbase + (size_t)t*TOKS + kc*128 + f4*4);
        PROJ_BFLY(a, y0, y1, y2, y3);
        const int r = f4 & 3;
        float4 sel;
        if      (r == 0) sel = y0;
        else if (r == 1) sel = y1;
        else if (r == 2) sel = y2;
        else             sel = y3;
        float4 po;
        po.x = __shfl_xor(sel.x, 32); po.y = __shfl_xor(sel.y, 32);
        po.z = __shfl_xor(sel.z, 32); po.w = __shfl_xor(sel.w, 32);
        if (lane < 32) {                      // own=even token, po=odd token
            const int n0 = (f4 >> 2)*16 + r*4;
            const int pair = p >> 6;
            *(unsigned*)((char*)Zt + (((n0+0)*128 + pair*4) ^ ZSWZ(n0+0))) = pk2(sel.x, po.x);
            *(unsigned*)((char*)Zt + (((n0+1)*128 + pair*4) ^ ZSWZ(n0+1))) = pk2(sel.y, po.y);
            *(unsigned*)((char*)Zt + (((n0+2)*128 + pair*4) ^ ZSWZ(n0+2))) = pk2(sel.z, po.z);
            *(unsigned*)((char*)Zt + (((n0+3)*128 + pair*4) ^ ZSWZ(n0+3))) = pk2(sel.w, po.w);
        }
    }
    __syncthreads();

    // MFMA + direct global store (4 rows x 64B full sectors per instruction)
    float* obase = out + (size_t)b*NT*TOKS + h*HSL + kc*128;
    #pragma unroll
    for (int nt2 = 0; nt2 < 8; ++nt2) {
        const int n    = nt2*16 + (lane & 15);
        const int swzn = ZSWZ(n);
        const bf16x8 bf0 = *(const bf16x8*)((const char*)Zt + ((n*128 +      (lane >> 4)*16) ^ swzn));
        const bf16x8 bf1 = *(const bf16x8*)((const char*)Zt + ((n*128 + 64 + (lane >> 4)*16) ^ swzn));
        f32x4 acc = (f32x4){0.f, 0.f, 0.f, 0.f};
        acc = __builtin_amdgcn_mfma_f32_16x16x32_bf16(af0, bf0, acc, 0, 0, 0);
        acc = __builtin_amdgcn_mfma_f32_16x16x32_bf16(af1, bf1, acc, 0, 0, 0);
        const float bias = bvoSh[n & 15];
        #pragma unroll
        for (int r2 = 0; r2 < 4; ++r2) {
            const int row = wv*16 + (lane >> 4)*4 + r2;
            if (row < NT) obase[(size_t)row*TOKS + n] = acc[r2] + bias;
        }
    }
}

extern "C" void kernel_launch(void* const* d_in, const int* in_sizes, int n_in,
                              void* d_out, int out_size, void* d_ws, size_t ws_size,
                              hipStream_t stream) {
    const float* v  = (const float*)d_in[0];
    const float* k  = (const float*)d_in[1];
    const float* q  = (const float*)d_in[2];
    const float* Wq = (const float*)d_in[3];
    const float* bq = (const float*)d_in[4];
    const float* Wk = (const float*)d_in[5];
    const float* bk = (const float*)d_in[6];   // softmax-row-invariant; unused
    const float* Wv = (const float*)d_in[7];
    const float* bv = (const float*)d_in[8];
    const float* Wo = (const float*)d_in[9];
    const float* bo = (const float*)d_in[10];
    (void)bk; (void)in_sizes; (void)n_in; (void)out_size;

    float* outp  = (float*)d_out;
    float* attnp = outp + (size_t)32 * 49 * 16384;      // out | attn concat
    float* ws1   = (float*)d_ws;

    const size_t need4 = (size_t)2048*SLOT*4 + (size_t)512*4096*2;
    if (ws_size >= need4) {
        ushort* ws2 = (ushort*)(ws1 + (size_t)2048*SLOT);
        k_scores<4,2><<<dim3(2048), dim3(256), 0, stream>>>(q, k, Wq, bq, Wk, ws1);
        k_softmax<4> <<<dim3(512),  dim3(256), 0, stream>>>(ws1, attnp, ws2);
        k_out        <<<dim3(4096), dim3(256), 0, stream>>>(v, Wv, bv, Wo, bo, ws2, outp);
    } else {
        ushort* ws2 = (ushort*)(ws1 + (size_t)1024*SLOT);
        k_scores<2,1><<<dim3(1024), dim3(256), 0, stream>>>(q, k, Wq, bq, Wk, ws1);
        k_softmax<2> <<<dim3(512),  dim3(256), 0, stream>>>(ws1, attnp, ws2);
        k_out        <<<dim3(4096), dim3(256), 0, stream>>>(v, Wv, bv, Wo, bo, ws2, outp);
    }
}

// Round 8
// 152.498 us; speedup vs baseline: 4.3114x; 1.1434x over previous
//
#include <hip/hip_runtime.h>
#include <hip/hip_bf16.h>

// LFA_self — 3-kernel pipeline for MI355X (round 8).
// scores = Xq (Wq Wk^T) Xk^T + g(t2); out = attn . (Xv (Wv Wo)) + (bv Wo + bo).
// Round-8: staging loads are BATCHED into registers before first use (one
// vmcnt drain per chunk instead of 13 serial load->use latencies). Index
// algebra: p = tid + 256 i  ->  f4 = tid&31 (invariant), t = (tid>>5) + 8 i.

#define NT 49
#define TOKS 16384
#define HSL 1024
#define SLOT 3200            // floats per partial slot: 49x64 scores + 64 g-tail
#define ZSWZ(n) (((((n) & 7) ^ (((n) >> 3) & 7))) << 4)

typedef __attribute__((ext_vector_type(8))) short bf16x8;
typedef __attribute__((ext_vector_type(4))) float f32x4;

__device__ __forceinline__ ushort f2bf(float f) {
    union { float f; unsigned u; } v; v.f = f;
    return (ushort)((v.u + 0x7fffu + ((v.u >> 16) & 1u)) >> 16);   // RNE
}
__device__ __forceinline__ unsigned pk2(float f0, float f1) {
    return (unsigned)f2bf(f0) | ((unsigned)f2bf(f1) << 16);
}
__device__ __forceinline__ float4 f4mul(float s, float4 w) {
    return make_float4(s*w.x, s*w.y, s*w.z, s*w.w);
}
__device__ __forceinline__ float4 f4fma(float s, float4 w, float4 a) {
    a.x = fmaf(s, w.x, a.x); a.y = fmaf(s, w.y, a.y);
    a.z = fmaf(s, w.z, a.z); a.w = fmaf(s, w.w, a.w);
    return a;
}
__device__ __forceinline__ float red4s(float v) {
    v += __shfl_xor(v, 1); v += __shfl_xor(v, 2); return v;
}
__device__ __forceinline__ float4 red4v(float4 v) {
    return make_float4(red4s(v.x), red4s(v.y), red4s(v.z), red4s(v.w));
}

// W preload: 16 named float4 = rows (lane&3)*4..+3 of a 16x16 row-major matrix
#define W_DECL(mb) \
    const float4 W00 = *(const float4*)((mb)+ 0), W01 = *(const float4*)((mb)+ 4), \
                 W02 = *(const float4*)((mb)+ 8), W03 = *(const float4*)((mb)+12), \
                 W10 = *(const float4*)((mb)+16), W11 = *(const float4*)((mb)+20), \
                 W12 = *(const float4*)((mb)+24), W13 = *(const float4*)((mb)+28), \
                 W20 = *(const float4*)((mb)+32), W21 = *(const float4*)((mb)+36), \
                 W22 = *(const float4*)((mb)+40), W23 = *(const float4*)((mb)+44), \
                 W30 = *(const float4*)((mb)+48), W31 = *(const float4*)((mb)+52), \
                 W32 = *(const float4*)((mb)+56), W33 = *(const float4*)((mb)+60)

#define PROJ_BFLY(a, y0, y1, y2, y3) \
    float4 y0 = f4mul((a).x, W00); y0 = f4fma((a).y, W10, y0); \
    y0 = f4fma((a).z, W20, y0);    y0 = f4fma((a).w, W30, y0); \
    float4 y1 = f4mul((a).x, W01); y1 = f4fma((a).y, W11, y1); \
    y1 = f4fma((a).z, W21, y1);    y1 = f4fma((a).w, W31, y1); \
    float4 y2 = f4mul((a).x, W02); y2 = f4fma((a).y, W12, y2); \
    y2 = f4fma((a).z, W22, y2);    y2 = f4fma((a).w, W32, y2); \
    float4 y3 = f4mul((a).x, W03); y3 = f4fma((a).y, W13, y3); \
    y3 = f4fma((a).z, W23, y3);    y3 = f4fma((a).w, W33, y3); \
    y0 = red4v(y0); y1 = red4v(y1); y2 = red4v(y2); y3 = red4v(y3)

// ===== K1: partial scores, grid (b,h,s)=512*SPLIT, 256 thr =================
template<int SPLIT, int LOG2S>
__global__ __launch_bounds__(256, 2) void k_scores(
    const float* __restrict__ qin, const float* __restrict__ kin,
    const float* __restrict__ Wq, const float* __restrict__ bq,
    const float* __restrict__ Wk, float* __restrict__ ws1)
{
    __shared__ ushort bufA[64*128];   // Yq bf16, 256B rows, XOR-swizzled
    __shared__ ushort bufB[64*128];   // Xk bf16, swizzled
    __shared__ float  Msh[256];       // Wq Wk^T
    __shared__ float  wkbqSh[16];     // Wk bq
    __shared__ float  gSh[64];

    const int tid  = threadIdx.x;
    const int lane = tid & 63;
    const int wv   = tid >> 6;        // 0..3
    const int s    = blockIdx.x & (SPLIT - 1);
    const int h    = (blockIdx.x >> LOG2S) & 15;
    const int b    = blockIdx.x >> (LOG2S + 4);

    const float* qbase = qin + (size_t)b*NT*TOKS + h*HSL + s*(1024/SPLIT);
    const float* kbase = kin + (size_t)b*NT*TOKS + h*HSL + s*(1024/SPLIT);

    {   // init: zero pad rows (49..63 must be 0 for MFMA), weight products
        unsigned* z0 = (unsigned*)bufA; unsigned* z1 = (unsigned*)bufB;
        for (int i = tid; i < 4096; i += 256) { z0[i] = 0u; z1[i] = 0u; }
        const int c1 = tid >> 4, c2 = tid & 15;
        float m = 0.f;
        #pragma unroll
        for (int f = 0; f < 16; ++f) m += Wq[c1*16+f] * Wk[c2*16+f];
        Msh[tid] = m;
        if (tid < 16) {
            float wb = 0.f;
            #pragma unroll
            for (int g = 0; g < 16; ++g) wb += Wk[tid*16+g] * bq[g];
            wkbqSh[tid] = wb;
        }
        if (tid < 64) gSh[tid] = 0.f;
    }
    __syncthreads();

    const float* mb = Msh + (lane & 3)*64;     // this lane's 4 rows of M
    W_DECL(mb);

    const int f4 = tid & 31;          // column group (iteration-invariant)
    const int t0 = tid >> 5;          // base token row
    const int r  = f4 & 3;

    f32x4 accS[4];
    #pragma unroll
    for (int nt = 0; nt < 4; ++nt) accS[nt] = (f32x4){0.f,0.f,0.f,0.f};

    for (int kc = 0; kc < 8/SPLIT; ++kc) {
        const float* qc = qbase + kc*128 + f4*4;
        const float* kp = kbase + kc*128 + f4*4;
        // ---- issue ALL 14 loads back-to-back (addr-clamped, no branches)
        float4 qv[7], kv[7];
        #pragma unroll
        for (int i = 0; i < 7; ++i) {
            const int t  = t0 + 8*i;
            const int tc = t < 48 ? t : 48;           // clamp: in-bounds always
            qv[i] = *(const float4*)(qc + (size_t)tc*TOKS);
            kv[i] = *(const float4*)(kp + (size_t)tc*TOKS);
        }
        // ---- process (single latency drain at first use)
        #pragma unroll
        for (int i = 0; i < 7; ++i) {
            const int t = t0 + 8*i;                   // t <= 55 < 64
            if (t >= NT) {
                qv[i] = make_float4(0.f,0.f,0.f,0.f);
                kv[i] = make_float4(0.f,0.f,0.f,0.f);
            }
            PROJ_BFLY(qv[i], y0, y1, y2, y3);
            uint2 w;
            if      (r == 0) { w.x = pk2(y0.x, y0.y); w.y = pk2(y0.z, y0.w); }
            else if (r == 1) { w.x = pk2(y1.x, y1.y); w.y = pk2(y1.z, y1.w); }
            else if (r == 2) { w.x = pk2(y2.x, y2.y); w.y = pk2(y2.z, y2.w); }
            else             { w.x = pk2(y3.x, y3.y); w.y = pk2(y3.z, y3.w); }
            const int addrA = (t*256 + (f4 >> 2)*32 + r*8) ^ ((t & 7) << 4);
            *(uint2*)((char*)bufA + addrA) = w;
            uint2 wk2; wk2.x = pk2(kv[i].x, kv[i].y); wk2.y = pk2(kv[i].z, kv[i].w);
            const int addrB = (t*256 + f4*8) ^ ((t & 7) << 4);
            *(uint2*)((char*)bufB + addrB) = wk2;
            const float* wb = wkbqSh + r*4;
            const float pg = kv[i].x*wb[0] + kv[i].y*wb[1] + kv[i].z*wb[2] + kv[i].w*wb[3];
            if (pg != 0.f) atomicAdd(&gSh[t], pg);    // bq==0 -> never fires
        }
        __syncthreads();
        #pragma unroll
        for (int ks = 0; ks < 4; ++ks) {
            const int ra  = wv*16 + (lane & 15);
            const int abo = (ra*256 + (ks*32 + (lane >> 4)*8)*2) ^ ((ra & 7) << 4);
            const bf16x8 af = *(const bf16x8*)((const char*)bufA + abo);
            #pragma unroll
            for (int nt = 0; nt < 4; ++nt) {
                const int rb  = nt*16 + (lane & 15);
                const int bbo = (rb*256 + (ks*32 + (lane >> 4)*8)*2) ^ ((rb & 7) << 4);
                const bf16x8 bf = *(const bf16x8*)((const char*)bufB + bbo);
                accS[nt] = __builtin_amdgcn_mfma_f32_16x16x32_bf16(af, bf, accS[nt], 0, 0, 0);
            }
        }
        __syncthreads();
    }

    float* slot = ws1 + (size_t)blockIdx.x * SLOT;
    #pragma unroll
    for (int nt = 0; nt < 4; ++nt) {
        const int col = nt*16 + (lane & 15);
        #pragma unroll
        for (int rr = 0; rr < 4; ++rr) {
            const int row = wv*16 + (lane >> 4)*4 + rr;
            if (row < NT) slot[row*64 + col] = accS[nt][rr];
        }
    }
    if (tid < 64) slot[3136 + tid] = gSh[tid];
}

// ===== K2: reduce + softmax, grid (b,h)=512, 256 thr =======================
template<int SPLIT>
__global__ __launch_bounds__(256, 2) void k_softmax(
    const float* __restrict__ ws1, float* __restrict__ attnp,
    ushort* __restrict__ ws2)
{
    __shared__ float sS[NT*69];
    __shared__ float sG[64];
    const int tid = threadIdx.x;
    const float* base = ws1 + (size_t)blockIdx.x * SPLIT * SLOT;

    for (int p = tid; p < 784; p += 256) {
        const int row = p >> 4, c4 = (p & 15) * 4;
        float4 acc = *(const float4*)(base + row*64 + c4);
        #pragma unroll
        for (int s = 1; s < SPLIT; ++s) {
            const float4 a = *(const float4*)(base + s*SLOT + row*64 + c4);
            acc.x += a.x; acc.y += a.y; acc.z += a.z; acc.w += a.w;
        }
        sS[row*69 + c4 + 0] = acc.x;
        sS[row*69 + c4 + 1] = acc.y;
        sS[row*69 + c4 + 2] = acc.z;
        sS[row*69 + c4 + 3] = acc.w;
    }
    if (tid < 64) {
        float g = base[3136 + tid];
        #pragma unroll
        for (int s = 1; s < SPLIT; ++s) g += base[s*SLOT + 3136 + tid];
        sG[tid] = g;
    }
    __syncthreads();

    if (tid < NT) {
        float mx = -1e30f;
        for (int j = 0; j < NT; ++j) {
            const float v = (sS[tid*69 + j] + sG[j]) * 0.03125f;
            sS[tid*69 + j] = v;
            mx = fmaxf(mx, v);
        }
        float ssum = 0.f;
        for (int j = 0; j < NT; ++j) {
            const float e = __expf(sS[tid*69 + j] - mx);
            sS[tid*69 + j] = e; ssum += e;
        }
        const float inv = 1.0f / ssum;
        for (int j = 0; j < NT; ++j) sS[tid*69 + j] *= inv;
    }
    __syncthreads();

    float* ab = attnp + (size_t)blockIdx.x * (NT*NT);
    for (int p = tid; p < NT*NT; p += 256) {
        const int t = p / NT, j = p - t*NT;
        ab[p] = sS[t*69 + j];
    }
    ushort* w2 = ws2 + (size_t)blockIdx.x * 4096;   // 64x64 bf16, zero-padded
    for (int p = tid; p < 4096; p += 256) {
        const int t = p >> 6, j = p & 63;
        const float v = (t < NT && j < NT) ? sS[t*69 + j] : 0.f;
        w2[p] = f2bf(v);
    }
}

// ===== K3: out = attn.Z + bvo, grid (b,h,kc)=4096, 256 thr =================
__global__ __launch_bounds__(256, 2) void k_out(
    const float* __restrict__ vin,
    const float* __restrict__ Wv, const float* __restrict__ bv,
    const float* __restrict__ Wo, const float* __restrict__ bo,
    const ushort* __restrict__ ws2, float* __restrict__ out)
{
    __shared__ unsigned Zt[4096];     // Z^T pair-packed: [128 n][32 kpair] u32
    __shared__ float WvoSh[256];
    __shared__ float bvoSh[16];

    const int tid  = threadIdx.x;
    const int lane = tid & 63;
    const int wv   = tid >> 6;        // 0..3 -> M-tile (token rows)
    const int kc   = blockIdx.x & 7;
    const int h    = (blockIdx.x >> 3) & 15;
    const int b    = blockIdx.x >> 7;
    const float* vbase = vin + (size_t)b*NT*TOKS + h*HSL;

    {
        const int c1 = tid >> 4, c2 = tid & 15;
        float wvo = 0.f;
        #pragma unroll
        for (int f = 0; f < 16; ++f) wvo += Wv[c1*16+f] * Wo[f*16+c2];
        WvoSh[tid] = wvo;
        if (tid < 16) {
            float s2 = 0.f;
            #pragma unroll
            for (int g = 0; g < 16; ++g) s2 += bv[g]*Wo[g*16+tid];
            bvoSh[tid] = s2 + bo[tid];
        }
        // zero k-pairs 25..31 (k rows 50..63; MFMA pad — avoid NaN*0)
        for (int i = tid; i < 1024; i += 256) {
            const int n = i >> 3, pr = 24 + (i & 7);
            if (pr >= 25)
                *(unsigned*)((char*)Zt + ((n*128 + pr*4) ^ ZSWZ(n))) = 0u;
        }
    }
    __syncthreads();

    // A-fragments from ws2 (global, L2/L3-hot; issue early to overlap staging)
    const ushort* w2 = ws2 + ((size_t)(blockIdx.x >> 3)) * 4096;
    const int ra = wv*16 + (lane & 15);
    const bf16x8 af0 = *(const bf16x8*)(w2 + ra*64 +      (lane >> 4)*8);
    const bf16x8 af1 = *(const bf16x8*)(w2 + ra*64 + 32 + (lane >> 4)*8);

    const float* mb = WvoSh + (lane & 3)*64;   // this lane's 4 rows of WvWo
    W_DECL(mb);

    const int f4 = tid & 31;
    const int t0 = tid >> 5;          // lanes<32: even token; lanes>=32: odd
    const int r  = f4 & 3;

    // ---- issue ALL 7 v loads back-to-back
    float4 vv[7];
    {
        const float* vc = vbase + kc*128 + f4*4;
        #pragma unroll
        for (int i = 0; i < 7; ++i) {
            const int t  = t0 + 8*i;
            const int tc = t < 48 ? t : 48;
            vv[i] = *(const float4*)(vc + (size_t)tc*TOKS);
        }
    }
    // ---- process: reg proj (butterfly) -> token-pair pack (xor 32) -> Zt
    #pragma unroll
    for (int i = 0; i < 7; ++i) {
        const int t = t0 + 8*i;
        if (t >= NT) vv[i] = make_float4(0.f,0.f,0.f,0.f);
        PROJ_BFLY(vv[i], y0, y1, y2, y3);
        float4 sel;
        if      (r == 0) sel = y0;
        else if (r == 1) sel = y1;
        else if (r == 2) sel = y2;
        else             sel = y3;
        float4 po;
        po.x = __shfl_xor(sel.x, 32); po.y = __shfl_xor(sel.y, 32);
        po.z = __shfl_xor(sel.z, 32); po.w = __shfl_xor(sel.w, 32);
        if (lane < 32) {                      // own=even token, po=odd token
            const int n0 = (f4 >> 2)*16 + r*4;
            const int pair = wv + 4*i;
            *(unsigned*)((char*)Zt + (((n0+0)*128 + pair*4) ^ ZSWZ(n0+0))) = pk2(sel.x, po.x);
            *(unsigned*)((char*)Zt + (((n0+1)*128 + pair*4) ^ ZSWZ(n0+1))) = pk2(sel.y, po.y);
            *(unsigned*)((char*)Zt + (((n0+2)*128 + pair*4) ^ ZSWZ(n0+2))) = pk2(sel.z, po.z);
            *(unsigned*)((char*)Zt + (((n0+3)*128 + pair*4) ^ ZSWZ(n0+3))) = pk2(sel.w, po.w);
        }
    }
    __syncthreads();

    // MFMA + direct global store (4 rows x 64B full sectors per instruction)
    float* obase = out + (size_t)b*NT*TOKS + h*HSL + kc*128;
    #pragma unroll
    for (int nt2 = 0; nt2 < 8; ++nt2) {
        const int n    = nt2*16 + (lane & 15);
        const int swzn = ZSWZ(n);
        const bf16x8 bf0 = *(const bf16x8*)((const char*)Zt + ((n*128 +      (lane >> 4)*16) ^ swzn));
        const bf16x8 bf1 = *(const bf16x8*)((const char*)Zt + ((n*128 + 64 + (lane >> 4)*16) ^ swzn));
        f32x4 acc = (f32x4){0.f, 0.f, 0.f, 0.f};
        acc = __builtin_amdgcn_mfma_f32_16x16x32_bf16(af0, bf0, acc, 0, 0, 0);
        acc = __builtin_amdgcn_mfma_f32_16x16x32_bf16(af1, bf1, acc, 0, 0, 0);
        const float bias = bvoSh[n & 15];
        #pragma unroll
        for (int r2 = 0; r2 < 4; ++r2) {
            const int row = wv*16 + (lane >> 4)*4 + r2;
            if (row < NT) obase[(size_t)row*TOKS + n] = acc[r2] + bias;
        }
    }
}

extern "C" void kernel_launch(void* const* d_in, const int* in_sizes, int n_in,
                              void* d_out, int out_size, void* d_ws, size_t ws_size,
                              hipStream_t stream) {
    const float* v  = (const float*)d_in[0];
    const float* k  = (const float*)d_in[1];
    const float* q  = (const float*)d_in[2];
    const float* Wq = (const float*)d_in[3];
    const float* bq = (const float*)d_in[4];
    const float* Wk = (const float*)d_in[5];
    const float* bk = (const float*)d_in[6];   // softmax-row-invariant; unused
    const float* Wv = (const float*)d_in[7];
    const float* bv = (const float*)d_in[8];
    const float* Wo = (const float*)d_in[9];
    const float* bo = (const float*)d_in[10];
    (void)bk; (void)in_sizes; (void)n_in; (void)out_size;

    float* outp  = (float*)d_out;
    float* attnp = outp + (size_t)32 * 49 * 16384;      // out | attn concat
    float* ws1   = (float*)d_ws;

    const size_t need4 = (size_t)2048*SLOT*4 + (size_t)512*4096*2;
    if (ws_size >= need4) {
        ushort* ws2 = (ushort*)(ws1 + (size_t)2048*SLOT);
        k_scores<4,2><<<dim3(2048), dim3(256), 0, stream>>>(q, k, Wq, bq, Wk, ws1);
        k_softmax<4> <<<dim3(512),  dim3(256), 0, stream>>>(ws1, attnp, ws2);
        k_out        <<<dim3(4096), dim3(256), 0, stream>>>(v, Wv, bv, Wo, bo, ws2, outp);
    } else {
        ushort* ws2 = (ushort*)(ws1 + (size_t)1024*SLOT);
        k_scores<2,1><<<dim3(1024), dim3(256), 0, stream>>>(q, k, Wq, bq, Wk, ws1);
        k_softmax<2> <<<dim3(512),  dim3(256), 0, stream>>>(ws1, attnp, ws2);
        k_out        <<<dim3(4096), dim3(256), 0, stream>>>(v, Wv, bv, Wo, bo, ws2, outp);
    }
}